// Round 18
// baseline (222.043 us; speedup 1.0000x reference)
//
#include <hip/hip_runtime.h>
#include <hip/hip_bf16.h>
#include <math.h>

// ---------------------------------------------------------------------------
// Shapes (compile-time constants for this problem)
// ---------------------------------------------------------------------------
#define SEQ     2048
#define D_MODEL 1024
#define D_IN    2048
#define N_STATE 16
#define DT_RANK 64
#define XDBL_W  96          // DT_RANK + 2*N_STATE
#define XDBL_LD 128         // padded leading dim of x_dbl
#define LC      64          // scan chunk length
#define NCH     32          // SEQ / LC
#define DT      32          // d-channels per scan block
#define WX_KSPLIT 16
#define WX_KSEG   (D_IN / WX_KSPLIT)   // 128
#define OUT_KSPLIT 4
#define OUT_KSEG   (D_IN / OUT_KSPLIT) // 512

#define LOG2E   1.4426950408889634f

typedef __attribute__((ext_vector_type(8))) _Float16 f16x8;
typedef __attribute__((ext_vector_type(4))) float f32x4;

__device__ __forceinline__ float fast_exp2(float x) { return __builtin_amdgcn_exp2f(x); }
__device__ __forceinline__ float fast_rcp(float x)  { return __builtin_amdgcn_rcpf(x); }

// fp32 <-> fp16 (RNE)
__device__ __forceinline__ ushort f2h(float x) {
    _Float16 h = (_Float16)x;
    return __builtin_bit_cast(ushort, h);
}
__device__ __forceinline__ float h2f(ushort u) {
    return (float)__builtin_bit_cast(_Float16, u);
}

// async global->LDS, 16 bytes/lane; LDS dest = wave-uniform base + lane*16.
__device__ __forceinline__ void gload16(const ushort* g, ushort* l) {
    __builtin_amdgcn_global_load_lds(
        (const __attribute__((address_space(1))) void*)g,
        (__attribute__((address_space(3))) void*)l, 16, 0, 0);
}

// Pre-swizzled-source staging (round-10/13 proven).
#define GL_DEFS                                                                \
    const int lane8 = lane >> 3;                                               \
    const int scol  = (lane & 7) ^ lane8;                                      \
    const int wq    = wave * 8;

#define STAGE_GL(SRC, DST, BASE, LDK, KOFF)                                    \
    _Pragma("unroll")                                                          \
    for (int q = 0; q < 4; ++q) {                                              \
        const int rr = q * 32 + wq + lane8;                                    \
        gload16(&SRC[(size_t)((BASE) + rr) * (LDK) + (KOFF) + scol * 8],       \
                ((ushort*)DST) + (q * 256 + wave * 64) * 8);                   \
    }

// fp16 2-pass inner compute for one 32-K slice (ks = 0/1).
#define COMPUTE_KS(KS)                                                         \
    {                                                                          \
        const int slot = ((((KS) << 2) | l4) ^ sw) * 8;                        \
        f16x8 ah[4], al[4], bb[4];                                             \
        _Pragma("unroll")                                                      \
        for (int f = 0; f < 4; ++f) {                                          \
            const int ar = mw + f * 16 + l15;                                  \
            const int br = nw + f * 16 + l15;                                  \
            ah[f] = *(const f16x8*)&lA[0][ar][slot];                           \
            al[f] = *(const f16x8*)&lA[1][ar][slot];                           \
            bb[f] = *(const f16x8*)&lB[br][slot];                              \
        }                                                                      \
        _Pragma("unroll")                                                      \
        for (int i = 0; i < 4; ++i)                                            \
            _Pragma("unroll")                                                  \
            for (int j = 0; j < 4; ++j) {                                      \
                acc[i][j] = __builtin_amdgcn_mfma_f32_16x16x32_f16(            \
                    ah[i], bb[j], acc[i][j], 0, 0, 0);                         \
                acc[i][j] = __builtin_amdgcn_mfma_f32_16x16x32_f16(            \
                    al[i], bb[j], acc[i][j], 0, 0, 0);                         \
            }                                                                  \
    }

// v_add_f32 with DPP-moved operand.
template <int CTRL>
__device__ __forceinline__ float dpp_add(float x) {
    int y = __builtin_amdgcn_update_dpp(0, __float_as_int(x), CTRL, 0xF, 0xF, true);
    return x + __int_as_float(y);
}

// ---------------------------------------------------------------------------
// split fp32 -> fp16 hi/lo (elementwise). One float4 per thread.
// ---------------------------------------------------------------------------
__global__ __launch_bounds__(256) void split_f16(
    const float* __restrict__ in, ushort* __restrict__ hi,
    ushort* __restrict__ lo)
{
    const int i = blockIdx.x * 256 + threadIdx.x;
    const float4 v = *(const float4*)&in[(size_t)i * 4];
    ushort4 h, l;
    h.x = f2h(v.x); l.x = f2h(v.x - h2f(h.x));
    h.y = f2h(v.y); l.y = f2h(v.y - h2f(h.y));
    h.z = f2h(v.z); l.z = f2h(v.z - h2f(h.z));
    h.w = f2h(v.w); l.w = f2h(v.w - h2f(h.w));
    *(ushort4*)&hi[(size_t)i * 4] = h;
    *(ushort4*)&lo[(size_t)i * 4] = l;
}

// ---------------------------------------------------------------------------
// transpose + fp16 convert: in[R][C] fp32 -> out[C][R] fp16.
// ---------------------------------------------------------------------------
__global__ __launch_bounds__(256) void trans_f16(
    const float* __restrict__ in, ushort* __restrict__ out, int R, int C)
{
    __shared__ float tile[32][33];
    const int c0 = blockIdx.x * 32;
    const int r0 = blockIdx.y * 32;
    const int tc = threadIdx.x & 31;
    const int tr = threadIdx.x >> 5;
#pragma unroll
    for (int q = 0; q < 4; ++q)
        tile[tr + 8 * q][tc] = in[(size_t)(r0 + tr + 8 * q) * C + c0 + tc];
    __syncthreads();
#pragma unroll
    for (int q = 0; q < 4; ++q)
        out[(size_t)(c0 + tr + 8 * q) * R + r0 + tc] = f2h(tile[tc][tr + 8 * q]);
}

__global__ __launch_bounds__(256) void trans_f16_pad(
    const float* __restrict__ in, ushort* __restrict__ out, int R, int Csrc)
{
    __shared__ float tile[32][33];
    const int c0 = blockIdx.x * 32;
    const int r0 = blockIdx.y * 32;
    const int tc = threadIdx.x & 31;
    const int tr = threadIdx.x >> 5;
#pragma unroll
    for (int q = 0; q < 4; ++q) {
        const int c = c0 + tc;
        tile[tr + 8 * q][tc] =
            (c < Csrc) ? in[(size_t)(r0 + tr + 8 * q) * Csrc + c] : 0.f;
    }
    __syncthreads();
#pragma unroll
    for (int q = 0; q < 4; ++q)
        out[(size_t)(c0 + tr + 8 * q) * R + r0 + tc] = f2h(tile[tc][tr + 8 * q]);
}

// ---------------------------------------------------------------------------
// fp16 2-pass MFMA GEMM (round-13 proven). C1 epilogue applies SiLU gate.
// ---------------------------------------------------------------------------
__global__ __launch_bounds__(256) void gemm_mfma3(
    const ushort* __restrict__ Ahi, const ushort* __restrict__ Alo,
    const ushort* __restrict__ Bf,
    float* __restrict__ C0, float* __restrict__ C1, int nsplit,
    int M, int N, int K, int ldc0, int ldc1)
{
    __shared__ ushort lA[2][128][64];   // 32 KB
    __shared__ ushort lB[128][64];      // 16 KB

    const int t    = threadIdx.x;
    const int m0   = blockIdx.y * 128;
    const int n0   = blockIdx.x * 128;
    const int wave = t >> 6;
    const int lane = t & 63;
    const int mw   = (wave & 1) * 64;
    const int nw   = (wave >> 1) * 64;
    const int l15  = lane & 15;
    const int l4   = lane >> 4;
    const int sw   = l15 & 7;
    GL_DEFS

    f32x4 acc[4][4];
#pragma unroll
    for (int i = 0; i < 4; ++i)
#pragma unroll
        for (int j = 0; j < 4; ++j)
            acc[i][j] = (f32x4){0.f, 0.f, 0.f, 0.f};

    for (int k0 = 0; k0 < K; k0 += 64) {
        __syncthreads();
        STAGE_GL(Ahi, lA[0], m0, K, k0)
        STAGE_GL(Alo, lA[1], m0, K, k0)
        STAGE_GL(Bf,  lB,    n0, K, k0)
        __syncthreads();
        COMPUTE_KS(0)
        COMPUTE_KS(1)
    }

#pragma unroll
    for (int i = 0; i < 4; ++i) {
        const int rowg = m0 + mw + i * 16 + l4 * 4;
#pragma unroll
        for (int j = 0; j < 4; ++j) {
            const int colg = n0 + nw + j * 16 + l15;
            if (colg < nsplit) {
#pragma unroll
                for (int v = 0; v < 4; ++v)
                    C0[(size_t)(rowg + v) * ldc0 + colg] = acc[i][j][v];
            } else {
                const int cc = colg - nsplit;
#pragma unroll
                for (int v = 0; v < 4; ++v) {
                    const float r = acc[i][j][v];
                    C1[(size_t)(rowg + v) * ldc1 + cc] =
                        r * fast_rcp(1.f + fast_exp2(-LOG2E * r));
                }
            }
        }
    }
}

// ---------------------------------------------------------------------------
// split-K MFMA GEMM for x_dbl = u @ W_x (N padded 96->128), fp16 2-pass.
// ---------------------------------------------------------------------------
__global__ __launch_bounds__(256) void gemm_wx_mfma(
    const ushort* __restrict__ Ahi, const ushort* __restrict__ Alo,
    const ushort* __restrict__ Bf, float* __restrict__ part)
{
    __shared__ ushort lA[2][128][64];
    __shared__ ushort lB[128][64];

    const int t    = threadIdx.x;
    const int kb   = blockIdx.x;
    const int m0   = blockIdx.y * 128;
    const int wave = t >> 6;
    const int lane = t & 63;
    const int mw   = (wave & 1) * 64;
    const int nw   = (wave >> 1) * 64;
    const int l15  = lane & 15;
    const int l4   = lane >> 4;
    const int sw   = l15 & 7;
    const int kbase = kb * WX_KSEG;
    GL_DEFS

    f32x4 acc[4][4];
#pragma unroll
    for (int i = 0; i < 4; ++i)
#pragma unroll
        for (int j = 0; j < 4; ++j)
            acc[i][j] = (f32x4){0.f, 0.f, 0.f, 0.f};

    for (int k0 = 0; k0 < WX_KSEG; k0 += 64) {
        __syncthreads();
        STAGE_GL(Ahi, lA[0], m0, D_IN, kbase + k0)
        STAGE_GL(Alo, lA[1], m0, D_IN, kbase + k0)
        STAGE_GL(Bf,  lB,    0,  D_IN, kbase + k0)
        __syncthreads();
        COMPUTE_KS(0)
        COMPUTE_KS(1)
    }

#pragma unroll
    for (int i = 0; i < 4; ++i) {
        const int rowg = m0 + mw + i * 16 + l4 * 4;
#pragma unroll
        for (int j = 0; j < 4; ++j) {
            const int colg = nw + j * 16 + l15;
#pragma unroll
            for (int v = 0; v < 4; ++v)
                part[((size_t)kb * SEQ + rowg + v) * XDBL_LD + colg] =
                    acc[i][j][v];
        }
    }
}

// Fixed-order reduction of the WX_KSPLIT partials -> xdbl [SEQ][XDBL_LD].
__global__ __launch_bounds__(256) void wx_reduce(
    const float* __restrict__ part, float* __restrict__ xdbl)
{
    const size_t i = (size_t)(blockIdx.x * 256 + threadIdx.x) * 4;
    float4 s = *(const float4*)&part[i];
#pragma unroll
    for (int kb = 1; kb < WX_KSPLIT; ++kb) {
        const float4 v = *(const float4*)&part[(size_t)kb * SEQ * XDBL_LD + i];
        s.x += v.x; s.y += v.y; s.z += v.z; s.w += v.w;
    }
    *(float4*)&xdbl[i] = s;
}

// ---------------------------------------------------------------------------
// split-K=4 MFMA GEMM for out = yg @ W_out, fp16 2-pass.
// ---------------------------------------------------------------------------
__global__ __launch_bounds__(256) void gemm_out_mfma(
    const ushort* __restrict__ Ahi, const ushort* __restrict__ Alo,
    const ushort* __restrict__ Bf,
    float* __restrict__ p01, float* __restrict__ p23)
{
    __shared__ ushort lA[2][128][64];
    __shared__ ushort lB[128][64];

    const int t    = threadIdx.x;
    const int n0   = blockIdx.x * 128;
    const int m0   = blockIdx.y * 128;
    const int kb   = blockIdx.z;
    const int wave = t >> 6;
    const int lane = t & 63;
    const int mw   = (wave & 1) * 64;
    const int nw   = (wave >> 1) * 64;
    const int l15  = lane & 15;
    const int l4   = lane >> 4;
    const int sw   = l15 & 7;
    const int kbase = kb * OUT_KSEG;
    GL_DEFS

    f32x4 acc[4][4];
#pragma unroll
    for (int i = 0; i < 4; ++i)
#pragma unroll
        for (int j = 0; j < 4; ++j)
            acc[i][j] = (f32x4){0.f, 0.f, 0.f, 0.f};

    for (int k0 = 0; k0 < OUT_KSEG; k0 += 64) {
        __syncthreads();
        STAGE_GL(Ahi, lA[0], m0, D_IN, kbase + k0)
        STAGE_GL(Alo, lA[1], m0, D_IN, kbase + k0)
        STAGE_GL(Bf,  lB,    n0, D_IN, kbase + k0)
        __syncthreads();
        COMPUTE_KS(0)
        COMPUTE_KS(1)
    }

    float* base = (kb & 2) ? p23 : p01;
    base += (size_t)(kb & 1) * SEQ * D_MODEL;
#pragma unroll
    for (int i = 0; i < 4; ++i) {
        const int rowg = m0 + mw + i * 16 + l4 * 4;
#pragma unroll
        for (int j = 0; j < 4; ++j) {
            const int colg = n0 + nw + j * 16 + l15;
#pragma unroll
            for (int v = 0; v < 4; ++v)
                base[(size_t)(rowg + v) * D_MODEL + colg] = acc[i][j][v];
        }
    }
}

// Fixed-order reduce of the 4 output partials -> out [SEQ][D_MODEL].
__global__ __launch_bounds__(256) void out_reduce(
    const float* __restrict__ p01, const float* __restrict__ p23,
    float* __restrict__ out)
{
    const size_t i = (size_t)(blockIdx.x * 256 + threadIdx.x) * 4;
    const size_t MN = (size_t)SEQ * D_MODEL;
    const float4 a = *(const float4*)&p01[i];
    const float4 b = *(const float4*)&p01[i + MN];
    const float4 c = *(const float4*)&p23[i];
    const float4 d = *(const float4*)&p23[i + MN];
    float4 s;
    s.x = ((a.x + b.x) + c.x) + d.x;
    s.y = ((a.y + b.y) + c.y) + d.y;
    s.z = ((a.z + b.z) + c.z) + d.z;
    s.w = ((a.w + b.w) + c.w) + d.w;
    *(float4*)&out[i] = s;
}

// ---------------------------------------------------------------------------
// delta GEMM, 64x64 tiles (K=64): 1024 blocks, ONE barrier, bounded unroll.
// Fused per-chunk double column sums (64-row tile == one chunk).
// ---------------------------------------------------------------------------
__global__ __launch_bounds__(256) void gemm_delta64(
    const float* __restrict__ A, const float* __restrict__ B,
    const float* __restrict__ bias, float* __restrict__ C,
    double* __restrict__ csumOut)
{
    __shared__ float At[64][68];
    __shared__ float Bs[64][68];
    __shared__ double dpart[16][64];

    const int t  = threadIdx.x;
    const int n0 = blockIdx.x * 64;
    const int m0 = blockIdx.y * 64;

    {
        const int r   = t >> 2;
        const int c16 = (t & 3) * 16;
#pragma unroll
        for (int q = 0; q < 4; ++q) {
            const float4 v =
                *(const float4*)&A[(size_t)(m0 + r) * XDBL_LD + c16 + q * 4];
            At[c16 + q * 4 + 0][r] = v.x;
            At[c16 + q * 4 + 1][r] = v.y;
            At[c16 + q * 4 + 2][r] = v.z;
            At[c16 + q * 4 + 3][r] = v.w;
        }
#pragma unroll
        for (int q = 0; q < 4; ++q)
            *(float4*)&Bs[r][c16 + q * 4] =
                *(const float4*)&B[(size_t)r * D_IN + n0 + c16 + q * 4];
    }
    __syncthreads();

    const int tx = t & 15;
    const int ty = t >> 4;
    float acc[4][4];
#pragma unroll
    for (int i = 0; i < 4; ++i)
#pragma unroll
        for (int j = 0; j < 4; ++j) acc[i][j] = 0.f;

#pragma unroll 1
    for (int k0 = 0; k0 < 64; k0 += 8) {
#pragma unroll
        for (int kk = 0; kk < 8; ++kk) {
            const int k = k0 + kk;
            const float4 a = *(const float4*)&At[k][ty * 4];
            const float4 b = *(const float4*)&Bs[k][tx * 4];
            const float av[4] = {a.x, a.y, a.z, a.w};
            const float bv[4] = {b.x, b.y, b.z, b.w};
#pragma unroll
            for (int i = 0; i < 4; ++i)
#pragma unroll
                for (int j = 0; j < 4; ++j)
                    acc[i][j] = fmaf(av[i], bv[j], acc[i][j]);
        }
    }

    double dsum[4];
#pragma unroll
    for (int j = 0; j < 4; ++j) dsum[j] = 0.0;
#pragma unroll
    for (int i = 0; i < 4; ++i) {
        float vals[4];
#pragma unroll
        for (int j = 0; j < 4; ++j) {
            float v = acc[i][j] + bias[n0 + tx * 4 + j];
            v = (v > 20.f) ? v : log1pf(__expf(v));   // softplus
            vals[j] = v;
            dsum[j] += (double)v;
        }
        *(float4*)&C[(size_t)(m0 + ty * 4 + i) * D_IN + n0 + tx * 4] =
            *(float4*)vals;
    }
#pragma unroll
    for (int j = 0; j < 4; ++j) dpart[ty][tx * 4 + j] = dsum[j];
    __syncthreads();
    if (t < 64) {
        double s = 0.0;
#pragma unroll
        for (int q = 0; q < 16; ++q) s += dpart[q][t];
        csumOut[(size_t)(m0 >> 6) * D_IN + n0 + t] = s;
    }
}

// ---------------------------------------------------------------------------
// Depthwise causal conv (K=3) + SiLU, fused with fp16 hi/lo split of u.
// ---------------------------------------------------------------------------
__global__ __launch_bounds__(256) void conv_silu_split(
    const float* __restrict__ xi, const float* __restrict__ cw,
    float* __restrict__ u, ushort* __restrict__ uhi, ushort* __restrict__ ulo)
{
    const int id = blockIdx.x * 256 + threadIdx.x;
    const int l = id >> 11;
    const int d = id & (D_IN - 1);
    const float w0 = cw[d * 3 + 0];
    const float w1 = cw[d * 3 + 1];
    const float w2 = cw[d * 3 + 2];
    const float x0  = xi[(size_t)l * D_IN + d];
    const float xm1 = (l >= 1) ? xi[(size_t)(l - 1) * D_IN + d] : 0.f;
    const float xm2 = (l >= 2) ? xi[(size_t)(l - 2) * D_IN + d] : 0.f;
    const float v = w0 * xm2 + w1 * xm1 + w2 * x0;
    const float s = fast_rcp(1.f + fast_exp2(-LOG2E * v));
    const float uu = v * s;
    u[id] = uu;
    const ushort h = f2h(uu);
    uhi[id] = h;
    ulo[id] = f2h(uu - h2f(h));
}

// ---------------------------------------------------------------------------
// SEGMENTED in-LDS sfx phase (shared by partA/partC), 256 threads:
//   dl=t>>3 (d-local), sg=t&7 (segment). READY(i,dl) reads staged delta,
//   WRITE(i,dl,v) stores sfx. Uses segsum[DT][8] + p0t[DT][2] (2.5 KB).
// Order differs from serial only by double-rounding (~1e-16 rel; clamped).
// ---------------------------------------------------------------------------
#define SFX_PHASE(READY, WRITE)                                                \
    {                                                                          \
        const int dl2 = t >> 3;                                                \
        const int sg  = t & 7;                                                 \
        const int d2  = d0 + dl2;                                              \
        const int cseg = c >> 2, coff = c & 3;                                 \
        {                                                                      \
            double tseg = 0.0;                                                 \
            _Pragma("unroll")                                                  \
            for (int k = 0; k < 4; ++k)                                        \
                tseg += csum[(size_t)(sg * 4 + k) * D_IN + d2];                \
            segsum[dl2][sg] = tseg;                                            \
            if (sg == cseg) {                                                  \
                double pp = 0.0;                                               \
                for (int k = 0; k < coff; ++k)                                 \
                    pp += csum[(size_t)(sg * 4 + k) * D_IN + d2];              \
                p0t[dl2][0] = pp;                                              \
            }                                                                  \
        }                                                                      \
        __syncthreads();                                                       \
        if (t < DT) {                                                          \
            double T = 0.0, P0 = p0t[t][0];                                    \
            _Pragma("unroll")                                                  \
            for (int s = 0; s < 8; ++s) {                                      \
                T += segsum[t][s];                                             \
                if (s < cseg) P0 += segsum[t][s];                              \
            }                                                                  \
            p0t[t][0] = P0;                                                    \
            p0t[t][1] = T;                                                     \
        }                                                                      \
        __syncthreads();                                                       \
        {                                                                      \
            double ss = 0.0;                                                   \
            _Pragma("unroll")                                                  \
            for (int j = 0; j < 8; ++j)                                        \
                ss += (double)READY(sg * 8 + j, dl2);                          \
            segsum[dl2][sg] = ss;                                              \
        }                                                                      \
        __syncthreads();                                                       \
        if (t < DT) {                                                          \
            double P = p0t[t][0];                                              \
            _Pragma("unroll")                                                  \
            for (int s = 0; s < 8; ++s) {                                      \
                const double v = segsum[t][s];                                 \
                segsum[t][s] = P;                                              \
                P += v;                                                        \
            }                                                                  \
        }                                                                      \
        __syncthreads();                                                       \
        {                                                                      \
            const double T = p0t[dl2][1];                                      \
            double P = segsum[dl2][sg];                                        \
            _Pragma("unroll")                                                  \
            for (int j = 0; j < 8; ++j) {                                      \
                const int i = sg * 8 + j;                                      \
                P += (double)READY(i, dl2);                                    \
                WRITE(i, dl2, (float)fmax(T - P, 0.0));                        \
            }                                                                  \
        }                                                                      \
        __syncthreads();                                                       \
    }

// ---------------------------------------------------------------------------
// Pass A (cumsum form), 2 states/lane, segmented in-kernel sfx.
// ---------------------------------------------------------------------------
__global__ __launch_bounds__(256) void scan_partA(
    const float* __restrict__ delta, const float* __restrict__ u,
    const double* __restrict__ csum, const float* __restrict__ xdbl,
    const float* __restrict__ Alog, float* __restrict__ Wc)
{
    __shared__ float2 spA[LC][DT];     // (du, delta->sfx)  16 KB
    __shared__ float2 sbA[LC][8];      //                    4 KB
    __shared__ double segsum[DT][8];   //                    2 KB
    __shared__ double p0t[DT][2];      //                    0.5 KB

    const int t  = threadIdx.x;
    const int c  = blockIdx.x;
    const int d0 = blockIdx.y * DT;

#pragma unroll
    for (int q = 0; q < 8; ++q) {
        const int e = q * 256 + t;
        const int r = e >> 5, col = e & 31;
        const size_t row = (size_t)(c * LC + r) * D_IN + d0 + col;
        const float dv = delta[row];
        spA[r][col] = make_float2(dv * u[row], dv);
    }
#pragma unroll
    for (int q = 0; q < 2; ++q) {
        const int e = q * 256 + t;
        const int r = e >> 3, n8e = e & 7;
        const size_t base = (size_t)(c * LC + r) * XDBL_LD + DT_RANK;
        sbA[r][n8e] = make_float2(xdbl[base + n8e], xdbl[base + 8 + n8e]);
    }
    __syncthreads();

#define RD_A(i, dl) spA[i][dl].y
#define WR_A(i, dl, v) spA[i][dl].y = (v)
    SFX_PHASE(RD_A, WR_A)
#undef RD_A
#undef WR_A

    const int dq = t >> 3;
    const int n8 = t & 7;
    const int d  = d0 + dq;
    const float An2a = -expf(Alog[d * N_STATE + n8]) * LOG2E;
    const float An2b = -expf(Alog[d * N_STATE + n8 + 8]) * LOG2E;

    float W0 = 0.f, W1 = 0.f;
#pragma unroll
    for (int i = 0; i < LC; ++i) {
        const float2 p = spA[i][dq];
        const float2 b = sbA[i][n8];
        W0 = fmaf(p.x * b.x, fast_exp2(An2a * p.y), W0);
        W1 = fmaf(p.x * b.y, fast_exp2(An2b * p.y), W1);
    }
    const size_t o = ((size_t)c * D_IN + d) * N_STATE + n8;
    Wc[o]     = W0;
    Wc[o + 8] = W1;
}

// ---------------------------------------------------------------------------
// Pass B: exclusive prefix over chunks (plain adds; cumsum form).
// ---------------------------------------------------------------------------
__global__ __launch_bounds__(256) void scan_combine(float* __restrict__ Wc)
{
    const int id = blockIdx.x * 256 + threadIdx.x;   // (d,n)
    float W = 0.f;
    for (int c = 0; c < NCH; ++c) {
        const size_t idx = (size_t)c * (D_IN * N_STATE) + id;
        const float w = Wc[idx];
        Wc[idx] = W;
        W += w;
    }
}

// ---------------------------------------------------------------------------
// Pass C (cumsum form), 2 states/lane, segmented in-kernel sfx, direct
// fp16 hi/lo yg output.
// ---------------------------------------------------------------------------
__global__ __launch_bounds__(256) void scan_partC(
    const float* __restrict__ delta, const float* __restrict__ u,
    const float* __restrict__ xdbl, const float* __restrict__ W0buf,
    const double* __restrict__ csum, const float* __restrict__ Alog,
    const float* __restrict__ Dvec, const float* __restrict__ rgbuf,
    ushort* __restrict__ ygh, ushort* __restrict__ ygl)
{
    __shared__ float4 spack[LC][DT];   // (du, delta->sfx, u, rg) 32 KB
    __shared__ float4 sbc[LC][8];      //  4 KB
    __shared__ double segsum[DT][8];   //  2 KB
    __shared__ double p0t[DT][2];      //  0.5 KB

    const int t  = threadIdx.x;
    const int c  = blockIdx.x;
    const int d0 = blockIdx.y * DT;

#pragma unroll
    for (int q = 0; q < 8; ++q) {
        const int e = q * 256 + t;
        const int r = e >> 5, col = e & 31;
        const size_t row = (size_t)(c * LC + r) * D_IN + d0 + col;
        const float dv = delta[row];
        const float uv = u[row];
        spack[r][col] = make_float4(dv * uv, dv, uv, rgbuf[row]);
    }
#pragma unroll
    for (int q = 0; q < 2; ++q) {
        const int e = q * 256 + t;
        const int r = e >> 3, n8e = e & 7;
        const size_t base = (size_t)(c * LC + r) * XDBL_LD + DT_RANK;
        sbc[r][n8e] = make_float4(xdbl[base + n8e],      xdbl[base + 16 + n8e],
                                  xdbl[base + 8 + n8e],  xdbl[base + 24 + n8e]);
    }
    __syncthreads();

#define RD_C(i, dl) spack[i][dl].y
#define WR_C(i, dl, v) spack[i][dl].y = (v)
    SFX_PHASE(RD_C, WR_C)
#undef RD_C
#undef WR_C

    const int dq = t >> 3;
    const int n8 = t & 7;
    const int d  = d0 + dq;
    const float An2a = -expf(Alog[d * N_STATE + n8]) * LOG2E;
    const float An2b = -expf(Alog[d * N_STATE + n8 + 8]) * LOG2E;
    const float Dd = Dvec[d];

    const size_t wo = ((size_t)c * D_IN + d) * N_STATE + n8;
    float W0 = W0buf[wo];
    float W1 = W0buf[wo + 8];

#pragma unroll
    for (int i = 0; i < LC; ++i) {
        const float4 p  = spack[i][dq];
        const float4 bc = sbc[i][n8];
        const float E0 = fast_exp2(An2a * p.y);
        const float E1 = fast_exp2(An2b * p.y);
        W0 = fmaf(p.x * bc.x, E0, W0);
        W1 = fmaf(p.x * bc.z, E1, W1);
        const float xs0 = W0 * fast_rcp(E0 + 1e-12f);
        const float xs1 = W1 * fast_rcp(E1 + 1e-12f);
        float contrib = fmaf(xs0, bc.y, xs1 * bc.w);
        contrib = dpp_add<0xB1>(contrib);    // xor 1
        contrib = dpp_add<0x4E>(contrib);    // xor 2
        contrib = dpp_add<0x124>(contrib);   // row_ror:4
        if (n8 == 0) {
            const float ygv = fmaf(p.z, Dd, contrib) * p.w;
            const size_t row = (size_t)(c * LC + i) * D_IN + d;
            const ushort h = f2h(ygv);
            ygh[row] = h;
            ygl[row] = f2h(ygv - h2f(h));
        }
    }
}

// ---------------------------------------------------------------------------
// Launch.  Workspace (74.5 MB peak, time-multiplexed; ws proven >= 84.9 MB).
// ---------------------------------------------------------------------------
extern "C" void kernel_launch(void* const* d_in, const int* in_sizes, int n_in,
                              void* d_out, int out_size, void* d_ws, size_t ws_size,
                              hipStream_t stream)
{
    const float* x      = (const float*)d_in[0];
    const float* W_in   = (const float*)d_in[1];
    const float* conv_w = (const float*)d_in[2];
    const float* W_x    = (const float*)d_in[3];
    const float* W_del  = (const float*)d_in[4];
    const float* b_del  = (const float*)d_in[5];
    const float* A_log  = (const float*)d_in[6];
    const float* Dv     = (const float*)d_in[7];
    const float* W_out  = (const float*)d_in[8];
    float* out = (float*)d_out;

    char* ws = (char*)d_ws;
    float*  xi    = (float*)(ws + 0);
    float*  wxp   = (float*)(ws + 0);
    ushort* yg_hi = (ushort*)(ws + 0);
    ushort* yg_lo = (ushort*)(ws + 8388608);
    float*  rg    = (float*)(ws + 16777216);
    float*  p01   = (float*)(ws + 16777216);
    ushort* x_hi  = (ushort*)(ws + 33554432);
    ushort* x_lo  = (ushort*)(ws + 37748736);
    float*  u     = (float*)(ws + 33554432);
    ushort* wo    = (ushort*)(ws + 33554432);
    float*  xdbl  = (float*)(ws + 50331648);
    ushort* wi    = (ushort*)(ws + 51380224);
    ushort* u_hi  = (ushort*)(ws + 51380224);
    ushort* u_lo  = (ushort*)(ws + 59768832);
    float*  delta = (float*)(ws + 51380224);
    float*  p23   = (float*)(ws + 51380224);
    float*  Wc    = (float*)(ws + 68157440);
    double* csum  = (double*)(ws + 72351744);
    ushort* wx    = (ushort*)(ws + 73416704);

    // 1) W_in^T -> fp16
    trans_f16<<<dim3(4096 / 32, 1024 / 32), 256, 0, stream>>>(
        W_in, wi, 1024, 4096);

    // 2) x -> fp16 hi/lo
    split_f16<<<(SEQ * D_MODEL / 4) / 256, 256, 0, stream>>>(x, x_hi, x_lo);

    // 3) [xi | rg] = x @ W_in   (fp16 2-pass; C1 applies SiLU gate)
    gemm_mfma3<<<dim3(4096 / 128, 2048 / 128), 256, 0, stream>>>(
        x_hi, x_lo, wi, xi, rg, D_IN,
        SEQ, 2 * D_IN, D_MODEL, D_IN, D_IN);

    // 4) u = silu(conv(xi)) + u fp16 hi/lo (fused)
    conv_silu_split<<<(SEQ * D_IN) / 256, 256, 0, stream>>>(
        xi, conv_w, u, u_hi, u_lo);

    // 5) W_x^T padded -> fp16
    trans_f16_pad<<<dim3(XDBL_LD / 32, D_IN / 32), 256, 0, stream>>>(
        W_x, wx, D_IN, XDBL_W);

    // 6) x_dbl = u @ W_x  (split-K fp16 2-pass, fixed-order reduce)
    gemm_wx_mfma<<<dim3(WX_KSPLIT, SEQ / 128), 256, 0, stream>>>(
        u_hi, u_lo, wx, wxp);
    wx_reduce<<<(SEQ * XDBL_LD / 4) / 256, 256, 0, stream>>>(wxp, xdbl);

    // 7) delta = softplus(...) + fused per-chunk double column sums
    gemm_delta64<<<dim3(2048 / 64, 2048 / 64), 256, 0, stream>>>(
        xdbl, W_del, b_del, delta, csum);

    // 8) chunk-parallel scan (cumsum form, 2 states/lane, segmented sfx)
    scan_partA<<<dim3(NCH, D_IN / DT), 256, 0, stream>>>(
        delta, u, csum, xdbl, A_log, Wc);
    scan_combine<<<(D_IN * N_STATE) / 256, 256, 0, stream>>>(Wc);
    scan_partC<<<dim3(NCH, D_IN / DT), 256, 0, stream>>>(
        delta, u, xdbl, Wc, csum, A_log, Dv, rg, yg_hi, yg_lo);

    // 9) W_out^T -> fp16 (u dead; region reused)
    trans_f16<<<dim3(1024 / 32, 2048 / 32), 256, 0, stream>>>(
        W_out, wo, 2048, 1024);

    // 10) out = yg @ W_out  (split-K=4 fp16 2-pass; partials in dead regions)
    gemm_out_mfma<<<dim3(D_MODEL / 128, SEQ / 128, OUT_KSPLIT), 256, 0, stream>>>(
        yg_hi, yg_lo, wo, p01, p23);
    out_reduce<<<(SEQ * D_MODEL / 4) / 256, 256, 0, stream>>>(p01, p23, out);
}

// Round 19
// 207.762 us; speedup vs baseline: 1.0687x; 1.0687x over previous
//
#include <hip/hip_runtime.h>
#include <hip/hip_bf16.h>
#include <math.h>

// ---------------------------------------------------------------------------
// Shapes (compile-time constants for this problem)
// ---------------------------------------------------------------------------
#define SEQ     2048
#define D_MODEL 1024
#define D_IN    2048
#define N_STATE 16
#define DT_RANK 64
#define XDBL_W  96          // DT_RANK + 2*N_STATE
#define XDBL_LD 128         // padded leading dim of x_dbl
#define LC      64          // scan chunk length
#define NCH     32          // SEQ / LC
#define DT      32          // d-channels per scan block
#define WX_KSPLIT 16
#define WX_KSEG   (D_IN / WX_KSPLIT)   // 128
#define OUT_KSPLIT 4
#define OUT_KSEG   (D_IN / OUT_KSPLIT) // 512

#define LOG2E   1.4426950408889634f

typedef __attribute__((ext_vector_type(8))) _Float16 f16x8;
typedef __attribute__((ext_vector_type(4))) float f32x4;

__device__ __forceinline__ float fast_exp2(float x) { return __builtin_amdgcn_exp2f(x); }
__device__ __forceinline__ float fast_rcp(float x)  { return __builtin_amdgcn_rcpf(x); }

// fp32 <-> fp16 (RNE)
__device__ __forceinline__ ushort f2h(float x) {
    _Float16 h = (_Float16)x;
    return __builtin_bit_cast(ushort, h);
}
__device__ __forceinline__ float h2f(ushort u) {
    return (float)__builtin_bit_cast(_Float16, u);
}

// async global->LDS, 16 bytes/lane; LDS dest = wave-uniform base + lane*16.
__device__ __forceinline__ void gload16(const ushort* g, ushort* l) {
    __builtin_amdgcn_global_load_lds(
        (const __attribute__((address_space(1))) void*)g,
        (__attribute__((address_space(3))) void*)l, 16, 0, 0);
}

// Pre-swizzled-source staging (round-10/13 proven).
#define GL_DEFS                                                                \
    const int lane8 = lane >> 3;                                               \
    const int scol  = (lane & 7) ^ lane8;                                      \
    const int wq    = wave * 8;

#define STAGE_GL(SRC, DST, BASE, LDK, KOFF)                                    \
    _Pragma("unroll")                                                          \
    for (int q = 0; q < 4; ++q) {                                              \
        const int rr = q * 32 + wq + lane8;                                    \
        gload16(&SRC[(size_t)((BASE) + rr) * (LDK) + (KOFF) + scol * 8],       \
                ((ushort*)DST) + (q * 256 + wave * 64) * 8);                   \
    }

// fp16 2-pass inner compute for one 32-K slice (ks = 0/1).
#define COMPUTE_KS(KS)                                                         \
    {                                                                          \
        const int slot = ((((KS) << 2) | l4) ^ sw) * 8;                        \
        f16x8 ah[4], al[4], bb[4];                                             \
        _Pragma("unroll")                                                      \
        for (int f = 0; f < 4; ++f) {                                          \
            const int ar = mw + f * 16 + l15;                                  \
            const int br = nw + f * 16 + l15;                                  \
            ah[f] = *(const f16x8*)&lA[0][ar][slot];                           \
            al[f] = *(const f16x8*)&lA[1][ar][slot];                           \
            bb[f] = *(const f16x8*)&lB[br][slot];                              \
        }                                                                      \
        _Pragma("unroll")                                                      \
        for (int i = 0; i < 4; ++i)                                            \
            _Pragma("unroll")                                                  \
            for (int j = 0; j < 4; ++j) {                                      \
                acc[i][j] = __builtin_amdgcn_mfma_f32_16x16x32_f16(            \
                    ah[i], bb[j], acc[i][j], 0, 0, 0);                         \
                acc[i][j] = __builtin_amdgcn_mfma_f32_16x16x32_f16(            \
                    al[i], bb[j], acc[i][j], 0, 0, 0);                         \
            }                                                                  \
    }

// v_add_f32 with DPP-moved operand.
template <int CTRL>
__device__ __forceinline__ float dpp_add(float x) {
    int y = __builtin_amdgcn_update_dpp(0, __float_as_int(x), CTRL, 0xF, 0xF, true);
    return x + __int_as_float(y);
}

// ---------------------------------------------------------------------------
// split fp32 -> fp16 hi/lo (elementwise). One float4 per thread.
// ---------------------------------------------------------------------------
__global__ __launch_bounds__(256) void split_f16(
    const float* __restrict__ in, ushort* __restrict__ hi,
    ushort* __restrict__ lo)
{
    const int i = blockIdx.x * 256 + threadIdx.x;
    const float4 v = *(const float4*)&in[(size_t)i * 4];
    ushort4 h, l;
    h.x = f2h(v.x); l.x = f2h(v.x - h2f(h.x));
    h.y = f2h(v.y); l.y = f2h(v.y - h2f(h.y));
    h.z = f2h(v.z); l.z = f2h(v.z - h2f(h.z));
    h.w = f2h(v.w); l.w = f2h(v.w - h2f(h.w));
    *(ushort4*)&hi[(size_t)i * 4] = h;
    *(ushort4*)&lo[(size_t)i * 4] = l;
}

// ---------------------------------------------------------------------------
// transpose + fp16 convert: in[R][C] fp32 -> out[C][R] fp16.
// ---------------------------------------------------------------------------
__global__ __launch_bounds__(256) void trans_f16(
    const float* __restrict__ in, ushort* __restrict__ out, int R, int C)
{
    __shared__ float tile[32][33];
    const int c0 = blockIdx.x * 32;
    const int r0 = blockIdx.y * 32;
    const int tc = threadIdx.x & 31;
    const int tr = threadIdx.x >> 5;
#pragma unroll
    for (int q = 0; q < 4; ++q)
        tile[tr + 8 * q][tc] = in[(size_t)(r0 + tr + 8 * q) * C + c0 + tc];
    __syncthreads();
#pragma unroll
    for (int q = 0; q < 4; ++q)
        out[(size_t)(c0 + tr + 8 * q) * R + r0 + tc] = f2h(tile[tc][tr + 8 * q]);
}

__global__ __launch_bounds__(256) void trans_f16_pad(
    const float* __restrict__ in, ushort* __restrict__ out, int R, int Csrc)
{
    __shared__ float tile[32][33];
    const int c0 = blockIdx.x * 32;
    const int r0 = blockIdx.y * 32;
    const int tc = threadIdx.x & 31;
    const int tr = threadIdx.x >> 5;
#pragma unroll
    for (int q = 0; q < 4; ++q) {
        const int c = c0 + tc;
        tile[tr + 8 * q][tc] =
            (c < Csrc) ? in[(size_t)(r0 + tr + 8 * q) * Csrc + c] : 0.f;
    }
    __syncthreads();
#pragma unroll
    for (int q = 0; q < 4; ++q)
        out[(size_t)(c0 + tr + 8 * q) * R + r0 + tc] = f2h(tile[tc][tr + 8 * q]);
}

// ---------------------------------------------------------------------------
// fp16 2-pass MFMA GEMM (round-13 proven). C1 epilogue applies SiLU gate.
// ---------------------------------------------------------------------------
__global__ __launch_bounds__(256) void gemm_mfma3(
    const ushort* __restrict__ Ahi, const ushort* __restrict__ Alo,
    const ushort* __restrict__ Bf,
    float* __restrict__ C0, float* __restrict__ C1, int nsplit,
    int M, int N, int K, int ldc0, int ldc1)
{
    __shared__ ushort lA[2][128][64];   // 32 KB
    __shared__ ushort lB[128][64];      // 16 KB

    const int t    = threadIdx.x;
    const int m0   = blockIdx.y * 128;
    const int n0   = blockIdx.x * 128;
    const int wave = t >> 6;
    const int lane = t & 63;
    const int mw   = (wave & 1) * 64;
    const int nw   = (wave >> 1) * 64;
    const int l15  = lane & 15;
    const int l4   = lane >> 4;
    const int sw   = l15 & 7;
    GL_DEFS

    f32x4 acc[4][4];
#pragma unroll
    for (int i = 0; i < 4; ++i)
#pragma unroll
        for (int j = 0; j < 4; ++j)
            acc[i][j] = (f32x4){0.f, 0.f, 0.f, 0.f};

    for (int k0 = 0; k0 < K; k0 += 64) {
        __syncthreads();
        STAGE_GL(Ahi, lA[0], m0, K, k0)
        STAGE_GL(Alo, lA[1], m0, K, k0)
        STAGE_GL(Bf,  lB,    n0, K, k0)
        __syncthreads();
        COMPUTE_KS(0)
        COMPUTE_KS(1)
    }

#pragma unroll
    for (int i = 0; i < 4; ++i) {
        const int rowg = m0 + mw + i * 16 + l4 * 4;
#pragma unroll
        for (int j = 0; j < 4; ++j) {
            const int colg = n0 + nw + j * 16 + l15;
            if (colg < nsplit) {
#pragma unroll
                for (int v = 0; v < 4; ++v)
                    C0[(size_t)(rowg + v) * ldc0 + colg] = acc[i][j][v];
            } else {
                const int cc = colg - nsplit;
#pragma unroll
                for (int v = 0; v < 4; ++v) {
                    const float r = acc[i][j][v];
                    C1[(size_t)(rowg + v) * ldc1 + cc] =
                        r * fast_rcp(1.f + fast_exp2(-LOG2E * r));
                }
            }
        }
    }
}

// ---------------------------------------------------------------------------
// split-K MFMA GEMM for x_dbl = u @ W_x (N padded 96->128), fp16 2-pass.
// ---------------------------------------------------------------------------
__global__ __launch_bounds__(256) void gemm_wx_mfma(
    const ushort* __restrict__ Ahi, const ushort* __restrict__ Alo,
    const ushort* __restrict__ Bf, float* __restrict__ part)
{
    __shared__ ushort lA[2][128][64];
    __shared__ ushort lB[128][64];

    const int t    = threadIdx.x;
    const int kb   = blockIdx.x;
    const int m0   = blockIdx.y * 128;
    const int wave = t >> 6;
    const int lane = t & 63;
    const int mw   = (wave & 1) * 64;
    const int nw   = (wave >> 1) * 64;
    const int l15  = lane & 15;
    const int l4   = lane >> 4;
    const int sw   = l15 & 7;
    const int kbase = kb * WX_KSEG;
    GL_DEFS

    f32x4 acc[4][4];
#pragma unroll
    for (int i = 0; i < 4; ++i)
#pragma unroll
        for (int j = 0; j < 4; ++j)
            acc[i][j] = (f32x4){0.f, 0.f, 0.f, 0.f};

    for (int k0 = 0; k0 < WX_KSEG; k0 += 64) {
        __syncthreads();
        STAGE_GL(Ahi, lA[0], m0, D_IN, kbase + k0)
        STAGE_GL(Alo, lA[1], m0, D_IN, kbase + k0)
        STAGE_GL(Bf,  lB,    0,  D_IN, kbase + k0)
        __syncthreads();
        COMPUTE_KS(0)
        COMPUTE_KS(1)
    }

#pragma unroll
    for (int i = 0; i < 4; ++i) {
        const int rowg = m0 + mw + i * 16 + l4 * 4;
#pragma unroll
        for (int j = 0; j < 4; ++j) {
            const int colg = nw + j * 16 + l15;
#pragma unroll
            for (int v = 0; v < 4; ++v)
                part[((size_t)kb * SEQ + rowg + v) * XDBL_LD + colg] =
                    acc[i][j][v];
        }
    }
}

// Fixed-order reduction of the WX_KSPLIT partials -> xdbl [SEQ][XDBL_LD].
__global__ __launch_bounds__(256) void wx_reduce(
    const float* __restrict__ part, float* __restrict__ xdbl)
{
    const size_t i = (size_t)(blockIdx.x * 256 + threadIdx.x) * 4;
    float4 s = *(const float4*)&part[i];
#pragma unroll
    for (int kb = 1; kb < WX_KSPLIT; ++kb) {
        const float4 v = *(const float4*)&part[(size_t)kb * SEQ * XDBL_LD + i];
        s.x += v.x; s.y += v.y; s.z += v.z; s.w += v.w;
    }
    *(float4*)&xdbl[i] = s;
}

// ---------------------------------------------------------------------------
// split-K=4 MFMA GEMM for out = yg @ W_out, fp16 2-pass.
// ---------------------------------------------------------------------------
__global__ __launch_bounds__(256) void gemm_out_mfma(
    const ushort* __restrict__ Ahi, const ushort* __restrict__ Alo,
    const ushort* __restrict__ Bf,
    float* __restrict__ p01, float* __restrict__ p23)
{
    __shared__ ushort lA[2][128][64];
    __shared__ ushort lB[128][64];

    const int t    = threadIdx.x;
    const int n0   = blockIdx.x * 128;
    const int m0   = blockIdx.y * 128;
    const int kb   = blockIdx.z;
    const int wave = t >> 6;
    const int lane = t & 63;
    const int mw   = (wave & 1) * 64;
    const int nw   = (wave >> 1) * 64;
    const int l15  = lane & 15;
    const int l4   = lane >> 4;
    const int sw   = l15 & 7;
    const int kbase = kb * OUT_KSEG;
    GL_DEFS

    f32x4 acc[4][4];
#pragma unroll
    for (int i = 0; i < 4; ++i)
#pragma unroll
        for (int j = 0; j < 4; ++j)
            acc[i][j] = (f32x4){0.f, 0.f, 0.f, 0.f};

    for (int k0 = 0; k0 < OUT_KSEG; k0 += 64) {
        __syncthreads();
        STAGE_GL(Ahi, lA[0], m0, D_IN, kbase + k0)
        STAGE_GL(Alo, lA[1], m0, D_IN, kbase + k0)
        STAGE_GL(Bf,  lB,    n0, D_IN, kbase + k0)
        __syncthreads();
        COMPUTE_KS(0)
        COMPUTE_KS(1)
    }

    float* base = (kb & 2) ? p23 : p01;
    base += (size_t)(kb & 1) * SEQ * D_MODEL;
#pragma unroll
    for (int i = 0; i < 4; ++i) {
        const int rowg = m0 + mw + i * 16 + l4 * 4;
#pragma unroll
        for (int j = 0; j < 4; ++j) {
            const int colg = n0 + nw + j * 16 + l15;
#pragma unroll
            for (int v = 0; v < 4; ++v)
                base[(size_t)(rowg + v) * D_MODEL + colg] = acc[i][j][v];
        }
    }
}

// Fixed-order reduce of the 4 output partials -> out [SEQ][D_MODEL].
__global__ __launch_bounds__(256) void out_reduce(
    const float* __restrict__ p01, const float* __restrict__ p23,
    float* __restrict__ out)
{
    const size_t i = (size_t)(blockIdx.x * 256 + threadIdx.x) * 4;
    const size_t MN = (size_t)SEQ * D_MODEL;
    const float4 a = *(const float4*)&p01[i];
    const float4 b = *(const float4*)&p01[i + MN];
    const float4 c = *(const float4*)&p23[i];
    const float4 d = *(const float4*)&p23[i + MN];
    float4 s;
    s.x = ((a.x + b.x) + c.x) + d.x;
    s.y = ((a.y + b.y) + c.y) + d.y;
    s.z = ((a.z + b.z) + c.z) + d.z;
    s.w = ((a.w + b.w) + c.w) + d.w;
    *(float4*)&out[i] = s;
}

// ---------------------------------------------------------------------------
// delta GEMM, 64x64 tiles (K=64): 1024 blocks, ONE barrier, bounded unroll
// (round-16 proven: full unroll hit 256 VGPR + scratch spill).
// Fused per-chunk double column sums (64-row tile == one chunk).
// ---------------------------------------------------------------------------
__global__ __launch_bounds__(256) void gemm_delta64(
    const float* __restrict__ A,      // xdbl [SEQ][XDBL_LD], cols 0..63
    const float* __restrict__ B,      // W_delta [64][D_IN]
    const float* __restrict__ bias,   // b_delta [D_IN]
    float* __restrict__ C,            // delta [SEQ][D_IN]
    double* __restrict__ csumOut)     // [NCH][D_IN]
{
    __shared__ float At[64][68];
    __shared__ float Bs[64][68];
    __shared__ double dpart[16][64];

    const int t  = threadIdx.x;
    const int n0 = blockIdx.x * 64;
    const int m0 = blockIdx.y * 64;

    {
        const int r   = t >> 2;
        const int c16 = (t & 3) * 16;
#pragma unroll
        for (int q = 0; q < 4; ++q) {
            const float4 v =
                *(const float4*)&A[(size_t)(m0 + r) * XDBL_LD + c16 + q * 4];
            At[c16 + q * 4 + 0][r] = v.x;
            At[c16 + q * 4 + 1][r] = v.y;
            At[c16 + q * 4 + 2][r] = v.z;
            At[c16 + q * 4 + 3][r] = v.w;
        }
#pragma unroll
        for (int q = 0; q < 4; ++q)
            *(float4*)&Bs[r][c16 + q * 4] =
                *(const float4*)&B[(size_t)r * D_IN + n0 + c16 + q * 4];
    }
    __syncthreads();

    const int tx = t & 15;
    const int ty = t >> 4;
    float acc[4][4];
#pragma unroll
    for (int i = 0; i < 4; ++i)
#pragma unroll
        for (int j = 0; j < 4; ++j) acc[i][j] = 0.f;

#pragma unroll 1
    for (int k0 = 0; k0 < 64; k0 += 8) {
#pragma unroll
        for (int kk = 0; kk < 8; ++kk) {
            const int k = k0 + kk;
            const float4 a = *(const float4*)&At[k][ty * 4];
            const float4 b = *(const float4*)&Bs[k][tx * 4];
            const float av[4] = {a.x, a.y, a.z, a.w};
            const float bv[4] = {b.x, b.y, b.z, b.w};
#pragma unroll
            for (int i = 0; i < 4; ++i)
#pragma unroll
                for (int j = 0; j < 4; ++j)
                    acc[i][j] = fmaf(av[i], bv[j], acc[i][j]);
        }
    }

    double dsum[4];
#pragma unroll
    for (int j = 0; j < 4; ++j) dsum[j] = 0.0;
#pragma unroll
    for (int i = 0; i < 4; ++i) {
        float vals[4];
#pragma unroll
        for (int j = 0; j < 4; ++j) {
            float v = acc[i][j] + bias[n0 + tx * 4 + j];
            v = (v > 20.f) ? v : log1pf(__expf(v));   // softplus
            vals[j] = v;
            dsum[j] += (double)v;
        }
        *(float4*)&C[(size_t)(m0 + ty * 4 + i) * D_IN + n0 + tx * 4] =
            *(float4*)vals;
    }
#pragma unroll
    for (int j = 0; j < 4; ++j) dpart[ty][tx * 4 + j] = dsum[j];
    __syncthreads();
    if (t < 64) {
        double s = 0.0;
#pragma unroll
        for (int q = 0; q < 16; ++q) s += dpart[q][t];
        csumOut[(size_t)(m0 >> 6) * D_IN + n0 + t] = s;
    }
}

// ---------------------------------------------------------------------------
// Depthwise causal conv (K=3) + SiLU, fused with fp16 hi/lo split of u.
// ---------------------------------------------------------------------------
__global__ __launch_bounds__(256) void conv_silu_split(
    const float* __restrict__ xi, const float* __restrict__ cw,
    float* __restrict__ u, ushort* __restrict__ uhi, ushort* __restrict__ ulo)
{
    const int id = blockIdx.x * 256 + threadIdx.x;
    const int l = id >> 11;
    const int d = id & (D_IN - 1);
    const float w0 = cw[d * 3 + 0];
    const float w1 = cw[d * 3 + 1];
    const float w2 = cw[d * 3 + 2];
    const float x0  = xi[(size_t)l * D_IN + d];
    const float xm1 = (l >= 1) ? xi[(size_t)(l - 1) * D_IN + d] : 0.f;
    const float xm2 = (l >= 2) ? xi[(size_t)(l - 2) * D_IN + d] : 0.f;
    const float v = w0 * xm2 + w1 * xm1 + w2 * x0;
    const float s = fast_rcp(1.f + fast_exp2(-LOG2E * v));
    const float uu = v * s;
    u[id] = uu;
    const ushort h = f2h(uu);
    uhi[id] = h;
    ulo[id] = f2h(uu - h2f(h));
}

// ---------------------------------------------------------------------------
// Pass A (cumsum form), 2 states/lane, with IN-KERNEL sfx computation:
// phase 1 stages (du, delta); phase 2 (threads 0..31, one per d) replays
// the double csum-prefix + per-element prefix (bit-identical to the old
// sfx_precompute) overwriting .y with sfx in LDS; phase 3 = main loop.
// ---------------------------------------------------------------------------
__global__ __launch_bounds__(256) void scan_partA(
    const float* __restrict__ delta, const float* __restrict__ u,
    const double* __restrict__ csum, const float* __restrict__ xdbl,
    const float* __restrict__ Alog, float* __restrict__ Wc)
{
    __shared__ float2 spA[LC][DT];     // (du, delta->sfx)  16 KB
    __shared__ float2 sbA[LC][8];      // (B[n8], B[n8+8])   4 KB

    const int t  = threadIdx.x;
    const int c  = blockIdx.x;
    const int d0 = blockIdx.y * DT;

#pragma unroll
    for (int q = 0; q < 8; ++q) {
        const int e = q * 256 + t;
        const int r = e >> 5, col = e & 31;
        const size_t row = (size_t)(c * LC + r) * D_IN + d0 + col;
        const float dv = delta[row];
        spA[r][col] = make_float2(dv * u[row], dv);
    }
#pragma unroll
    for (int q = 0; q < 2; ++q) {
        const int e = q * 256 + t;
        const int r = e >> 3, n8e = e & 7;
        const size_t base = (size_t)(c * LC + r) * XDBL_LD + DT_RANK;
        sbA[r][n8e] = make_float2(xdbl[base + n8e], xdbl[base + 8 + n8e]);
    }
    __syncthreads();

    if (t < DT) {   // per-d double prefix -> sfx in LDS
        const int d = d0 + t;
        double S = 0.0, P = 0.0;
        for (int c2 = 0; c2 < NCH; ++c2) {
            if (c2 == c) P = S;
            S += csum[(size_t)c2 * D_IN + d];
        }
        for (int i = 0; i < LC; ++i) {
            P += (double)spA[i][t].y;
            spA[i][t].y = (float)fmax(S - P, 0.0);
        }
    }
    __syncthreads();

    const int dq = t >> 3;
    const int n8 = t & 7;
    const int d  = d0 + dq;
    const float An2a = -expf(Alog[d * N_STATE + n8]) * LOG2E;
    const float An2b = -expf(Alog[d * N_STATE + n8 + 8]) * LOG2E;

    float W0 = 0.f, W1 = 0.f;
#pragma unroll
    for (int i = 0; i < LC; ++i) {
        const float2 p = spA[i][dq];
        const float2 b = sbA[i][n8];
        W0 = fmaf(p.x * b.x, fast_exp2(An2a * p.y), W0);
        W1 = fmaf(p.x * b.y, fast_exp2(An2b * p.y), W1);
    }
    const size_t o = ((size_t)c * D_IN + d) * N_STATE + n8;
    Wc[o]     = W0;
    Wc[o + 8] = W1;
}

// ---------------------------------------------------------------------------
// Pass B: exclusive prefix over chunks (plain adds; cumsum form).
// ---------------------------------------------------------------------------
__global__ __launch_bounds__(256) void scan_combine(float* __restrict__ Wc)
{
    const int id = blockIdx.x * 256 + threadIdx.x;   // (d,n)
    float W = 0.f;
    for (int c = 0; c < NCH; ++c) {
        const size_t idx = (size_t)c * (D_IN * N_STATE) + id;
        const float w = Wc[idx];
        Wc[idx] = W;
        W += w;
    }
}

// ---------------------------------------------------------------------------
// Pass C (cumsum form), 2 states/lane, in-kernel sfx (phase 2 as partA),
// and DIRECT fp16 hi/lo output of yg (deletes the separate split pass).
// ---------------------------------------------------------------------------
__global__ __launch_bounds__(256) void scan_partC(
    const float* __restrict__ delta, const float* __restrict__ u,
    const float* __restrict__ xdbl, const float* __restrict__ W0buf,
    const double* __restrict__ csum, const float* __restrict__ Alog,
    const float* __restrict__ Dvec, const float* __restrict__ rgbuf,
    ushort* __restrict__ ygh, ushort* __restrict__ ygl)
{
    __shared__ float4 spack[LC][DT];   // (du, delta->sfx, u, rg) 32 KB
    __shared__ float4 sbc[LC][8];      //  4 KB

    const int t  = threadIdx.x;
    const int c  = blockIdx.x;
    const int d0 = blockIdx.y * DT;

#pragma unroll
    for (int q = 0; q < 8; ++q) {
        const int e = q * 256 + t;
        const int r = e >> 5, col = e & 31;
        const size_t row = (size_t)(c * LC + r) * D_IN + d0 + col;
        const float dv = delta[row];
        const float uv = u[row];
        spack[r][col] = make_float4(dv * uv, dv, uv, rgbuf[row]);
    }
#pragma unroll
    for (int q = 0; q < 2; ++q) {
        const int e = q * 256 + t;
        const int r = e >> 3, n8e = e & 7;
        const size_t base = (size_t)(c * LC + r) * XDBL_LD + DT_RANK;
        sbc[r][n8e] = make_float4(xdbl[base + n8e],      xdbl[base + 16 + n8e],
                                  xdbl[base + 8 + n8e],  xdbl[base + 24 + n8e]);
    }
    __syncthreads();

    if (t < DT) {   // per-d double prefix -> sfx in LDS (bit-identical)
        const int d = d0 + t;
        double S = 0.0, P = 0.0;
        for (int c2 = 0; c2 < NCH; ++c2) {
            if (c2 == c) P = S;
            S += csum[(size_t)c2 * D_IN + d];
        }
        for (int i = 0; i < LC; ++i) {
            P += (double)spack[i][t].y;
            spack[i][t].y = (float)fmax(S - P, 0.0);
        }
    }
    __syncthreads();

    const int dq = t >> 3;
    const int n8 = t & 7;
    const int d  = d0 + dq;
    const float An2a = -expf(Alog[d * N_STATE + n8]) * LOG2E;
    const float An2b = -expf(Alog[d * N_STATE + n8 + 8]) * LOG2E;
    const float Dd = Dvec[d];

    const size_t wo = ((size_t)c * D_IN + d) * N_STATE + n8;
    float W0 = W0buf[wo];
    float W1 = W0buf[wo + 8];

#pragma unroll
    for (int i = 0; i < LC; ++i) {
        const float4 p  = spack[i][dq];
        const float4 bc = sbc[i][n8];
        const float E0 = fast_exp2(An2a * p.y);
        const float E1 = fast_exp2(An2b * p.y);
        W0 = fmaf(p.x * bc.x, E0, W0);
        W1 = fmaf(p.x * bc.z, E1, W1);
        const float xs0 = W0 * fast_rcp(E0 + 1e-12f);
        const float xs1 = W1 * fast_rcp(E1 + 1e-12f);
        float contrib = fmaf(xs0, bc.y, xs1 * bc.w);
        contrib = dpp_add<0xB1>(contrib);    // xor 1
        contrib = dpp_add<0x4E>(contrib);    // xor 2
        contrib = dpp_add<0x124>(contrib);   // row_ror:4
        if (n8 == 0) {
            const float ygv = fmaf(p.z, Dd, contrib) * p.w;
            const size_t row = (size_t)(c * LC + i) * D_IN + d;
            const ushort h = f2h(ygv);
            ygh[row] = h;
            ygl[row] = f2h(ygv - h2f(h));
        }
    }
}

// ---------------------------------------------------------------------------
// Launch.  Workspace (74.5 MB peak, time-multiplexed; ws proven >= 84.9 MB):
//   [ 0    ,16.78M): xi -> wxp -> yg_hi/yg_lo (written by partC)
//   [16.78 ,33.55 ): rg (gemm1 epilogue) -> out partials p01
//   [33.55 ,50.33 ): x_hi/x_lo -> u (f32) -> wo (fp16)
//   [50.33 ,51.38 ): xdbl [2048][128] f32
//   [51.38 ,68.16 ): wi (fp16) -> u_hi/u_lo -> delta -> p23
//   [68.16 ,73.42 ): Wc/W0, csum
//   [73.42 ,74.47 ): wx (fp16)
// ---------------------------------------------------------------------------
extern "C" void kernel_launch(void* const* d_in, const int* in_sizes, int n_in,
                              void* d_out, int out_size, void* d_ws, size_t ws_size,
                              hipStream_t stream)
{
    const float* x      = (const float*)d_in[0];
    const float* W_in   = (const float*)d_in[1];
    const float* conv_w = (const float*)d_in[2];
    const float* W_x    = (const float*)d_in[3];
    const float* W_del  = (const float*)d_in[4];
    const float* b_del  = (const float*)d_in[5];
    const float* A_log  = (const float*)d_in[6];
    const float* Dv     = (const float*)d_in[7];
    const float* W_out  = (const float*)d_in[8];
    float* out = (float*)d_out;

    char* ws = (char*)d_ws;
    float*  xi    = (float*)(ws + 0);
    float*  wxp   = (float*)(ws + 0);
    ushort* yg_hi = (ushort*)(ws + 0);
    ushort* yg_lo = (ushort*)(ws + 8388608);
    float*  rg    = (float*)(ws + 16777216);   // gemm1 epilogue: res*sigmoid(res)
    float*  p01   = (float*)(ws + 16777216);
    ushort* x_hi  = (ushort*)(ws + 33554432);
    ushort* x_lo  = (ushort*)(ws + 37748736);
    float*  u     = (float*)(ws + 33554432);
    ushort* wo    = (ushort*)(ws + 33554432);  // [1024][2048] fp16
    float*  xdbl  = (float*)(ws + 50331648);
    ushort* wi    = (ushort*)(ws + 51380224);  // [4096][1024] fp16
    ushort* u_hi  = (ushort*)(ws + 51380224);
    ushort* u_lo  = (ushort*)(ws + 59768832);
    float*  delta = (float*)(ws + 51380224);
    float*  p23   = (float*)(ws + 51380224);
    float*  Wc    = (float*)(ws + 68157440);   // 4.19 MB
    double* csum  = (double*)(ws + 72351744);  // 0.52 MB
    ushort* wx    = (ushort*)(ws + 73416704);  // [128][2048] fp16

    // 1) W_in^T -> fp16
    trans_f16<<<dim3(4096 / 32, 1024 / 32), 256, 0, stream>>>(
        W_in, wi, 1024, 4096);

    // 2) x -> fp16 hi/lo
    split_f16<<<(SEQ * D_MODEL / 4) / 256, 256, 0, stream>>>(x, x_hi, x_lo);

    // 3) [xi | rg] = x @ W_in   (fp16 2-pass; C1 applies SiLU gate)
    gemm_mfma3<<<dim3(4096 / 128, 2048 / 128), 256, 0, stream>>>(
        x_hi, x_lo, wi, xi, rg, D_IN,
        SEQ, 2 * D_IN, D_MODEL, D_IN, D_IN);

    // 4) u = silu(conv(xi)) + u fp16 hi/lo (fused)
    conv_silu_split<<<(SEQ * D_IN) / 256, 256, 0, stream>>>(
        xi, conv_w, u, u_hi, u_lo);

    // 5) W_x^T padded -> fp16
    trans_f16_pad<<<dim3(XDBL_LD / 32, D_IN / 32), 256, 0, stream>>>(
        W_x, wx, D_IN, XDBL_W);

    // 6) x_dbl = u @ W_x  (split-K fp16 2-pass, fixed-order reduce)
    gemm_wx_mfma<<<dim3(WX_KSPLIT, SEQ / 128), 256, 0, stream>>>(
        u_hi, u_lo, wx, wxp);
    wx_reduce<<<(SEQ * XDBL_LD / 4) / 256, 256, 0, stream>>>(wxp, xdbl);

    // 7) delta = softplus(...) + fused per-chunk double column sums
    gemm_delta64<<<dim3(2048 / 64, 2048 / 64), 256, 0, stream>>>(
        xdbl, W_del, b_del, delta, csum);

    // 8) chunk-parallel scan (cumsum form, 2 states/lane, in-kernel sfx)
    scan_partA<<<dim3(NCH, D_IN / DT), 256, 0, stream>>>(
        delta, u, csum, xdbl, A_log, Wc);
    scan_combine<<<(D_IN * N_STATE) / 256, 256, 0, stream>>>(Wc);
    scan_partC<<<dim3(NCH, D_IN / DT), 256, 0, stream>>>(
        delta, u, xdbl, Wc, csum, A_log, Dv, rg, yg_hi, yg_lo);

    // 9) W_out^T -> fp16 (u dead; region reused)
    trans_f16<<<dim3(1024 / 32, 2048 / 32), 256, 0, stream>>>(
        W_out, wo, 2048, 1024);

    // 10) out = yg @ W_out  (split-K=4 fp16 2-pass; partials in dead regions)
    gemm_out_mfma<<<dim3(D_MODEL / 128, SEQ / 128, OUT_KSPLIT), 256, 0, stream>>>(
        yg_hi, yg_lo, wo, p01, p23);
    out_reduce<<<(SEQ * D_MODEL / 4) / 256, 256, 0, stream>>>(p01, p23, out);
}

// Round 20
// 204.865 us; speedup vs baseline: 1.0839x; 1.0141x over previous
//
#include <hip/hip_runtime.h>
#include <hip/hip_bf16.h>
#include <math.h>

// ---------------------------------------------------------------------------
// Shapes (compile-time constants for this problem)
// ---------------------------------------------------------------------------
#define SEQ     2048
#define D_MODEL 1024
#define D_IN    2048
#define N_STATE 16
#define DT_RANK 64
#define XDBL_W  96          // DT_RANK + 2*N_STATE
#define XDBL_LD 128         // padded leading dim of x_dbl
#define LC      64          // scan chunk length
#define LH      32          // half-chunk (LDS tile) length
#define NCH     32          // SEQ / LC
#define DT      32          // d-channels per scan block
#define WX_KSPLIT 16
#define WX_KSEG   (D_IN / WX_KSPLIT)   // 128
#define OUT_KSPLIT 4
#define OUT_KSEG   (D_IN / OUT_KSPLIT) // 512

#define LOG2E   1.4426950408889634f

typedef __attribute__((ext_vector_type(8))) _Float16 f16x8;
typedef __attribute__((ext_vector_type(4))) float f32x4;

__device__ __forceinline__ float fast_exp2(float x) { return __builtin_amdgcn_exp2f(x); }
__device__ __forceinline__ float fast_rcp(float x)  { return __builtin_amdgcn_rcpf(x); }

// fp32 <-> fp16 (RNE)
__device__ __forceinline__ ushort f2h(float x) {
    _Float16 h = (_Float16)x;
    return __builtin_bit_cast(ushort, h);
}
__device__ __forceinline__ float h2f(ushort u) {
    return (float)__builtin_bit_cast(_Float16, u);
}

// async global->LDS, 16 bytes/lane; LDS dest = wave-uniform base + lane*16.
__device__ __forceinline__ void gload16(const ushort* g, ushort* l) {
    __builtin_amdgcn_global_load_lds(
        (const __attribute__((address_space(1))) void*)g,
        (__attribute__((address_space(3))) void*)l, 16, 0, 0);
}

// Pre-swizzled-source staging (round-10/13 proven).
#define GL_DEFS                                                                \
    const int lane8 = lane >> 3;                                               \
    const int scol  = (lane & 7) ^ lane8;                                      \
    const int wq    = wave * 8;

#define STAGE_GL(SRC, DST, BASE, LDK, KOFF)                                    \
    _Pragma("unroll")                                                          \
    for (int q = 0; q < 4; ++q) {                                              \
        const int rr = q * 32 + wq + lane8;                                    \
        gload16(&SRC[(size_t)((BASE) + rr) * (LDK) + (KOFF) + scol * 8],       \
                ((ushort*)DST) + (q * 256 + wave * 64) * 8);                   \
    }

// fp16 2-pass inner compute for one 32-K slice (ks = 0/1).
#define COMPUTE_KS(KS)                                                         \
    {                                                                          \
        const int slot = ((((KS) << 2) | l4) ^ sw) * 8;                        \
        f16x8 ah[4], al[4], bb[4];                                             \
        _Pragma("unroll")                                                      \
        for (int f = 0; f < 4; ++f) {                                          \
            const int ar = mw + f * 16 + l15;                                  \
            const int br = nw + f * 16 + l15;                                  \
            ah[f] = *(const f16x8*)&lA[0][ar][slot];                           \
            al[f] = *(const f16x8*)&lA[1][ar][slot];                           \
            bb[f] = *(const f16x8*)&lB[br][slot];                              \
        }                                                                      \
        _Pragma("unroll")                                                      \
        for (int i = 0; i < 4; ++i)                                            \
            _Pragma("unroll")                                                  \
            for (int j = 0; j < 4; ++j) {                                      \
                acc[i][j] = __builtin_amdgcn_mfma_f32_16x16x32_f16(            \
                    ah[i], bb[j], acc[i][j], 0, 0, 0);                         \
                acc[i][j] = __builtin_amdgcn_mfma_f32_16x16x32_f16(            \
                    al[i], bb[j], acc[i][j], 0, 0, 0);                         \
            }                                                                  \
    }

// v_add_f32 with DPP-moved operand.
template <int CTRL>
__device__ __forceinline__ float dpp_add(float x) {
    int y = __builtin_amdgcn_update_dpp(0, __float_as_int(x), CTRL, 0xF, 0xF, true);
    return x + __int_as_float(y);
}

// ---------------------------------------------------------------------------
// split fp32 -> fp16 hi/lo (elementwise). One float4 per thread.
// ---------------------------------------------------------------------------
__global__ __launch_bounds__(256) void split_f16(
    const float* __restrict__ in, ushort* __restrict__ hi,
    ushort* __restrict__ lo)
{
    const int i = blockIdx.x * 256 + threadIdx.x;
    const float4 v = *(const float4*)&in[(size_t)i * 4];
    ushort4 h, l;
    h.x = f2h(v.x); l.x = f2h(v.x - h2f(h.x));
    h.y = f2h(v.y); l.y = f2h(v.y - h2f(h.y));
    h.z = f2h(v.z); l.z = f2h(v.z - h2f(h.z));
    h.w = f2h(v.w); l.w = f2h(v.w - h2f(h.w));
    *(ushort4*)&hi[(size_t)i * 4] = h;
    *(ushort4*)&lo[(size_t)i * 4] = l;
}

// ---------------------------------------------------------------------------
// transpose + fp16 convert: in[R][C] fp32 -> out[C][R] fp16.
// ---------------------------------------------------------------------------
__global__ __launch_bounds__(256) void trans_f16(
    const float* __restrict__ in, ushort* __restrict__ out, int R, int C)
{
    __shared__ float tile[32][33];
    const int c0 = blockIdx.x * 32;
    const int r0 = blockIdx.y * 32;
    const int tc = threadIdx.x & 31;
    const int tr = threadIdx.x >> 5;
#pragma unroll
    for (int q = 0; q < 4; ++q)
        tile[tr + 8 * q][tc] = in[(size_t)(r0 + tr + 8 * q) * C + c0 + tc];
    __syncthreads();
#pragma unroll
    for (int q = 0; q < 4; ++q)
        out[(size_t)(c0 + tr + 8 * q) * R + r0 + tc] = f2h(tile[tc][tr + 8 * q]);
}

__global__ __launch_bounds__(256) void trans_f16_pad(
    const float* __restrict__ in, ushort* __restrict__ out, int R, int Csrc)
{
    __shared__ float tile[32][33];
    const int c0 = blockIdx.x * 32;
    const int r0 = blockIdx.y * 32;
    const int tc = threadIdx.x & 31;
    const int tr = threadIdx.x >> 5;
#pragma unroll
    for (int q = 0; q < 4; ++q) {
        const int c = c0 + tc;
        tile[tr + 8 * q][tc] =
            (c < Csrc) ? in[(size_t)(r0 + tr + 8 * q) * Csrc + c] : 0.f;
    }
    __syncthreads();
#pragma unroll
    for (int q = 0; q < 4; ++q)
        out[(size_t)(c0 + tr + 8 * q) * R + r0 + tc] = f2h(tile[tc][tr + 8 * q]);
}

// ---------------------------------------------------------------------------
// fp16 2-pass MFMA GEMM (round-13 proven). C1 epilogue applies SiLU gate.
// ---------------------------------------------------------------------------
__global__ __launch_bounds__(256) void gemm_mfma3(
    const ushort* __restrict__ Ahi, const ushort* __restrict__ Alo,
    const ushort* __restrict__ Bf,
    float* __restrict__ C0, float* __restrict__ C1, int nsplit,
    int M, int N, int K, int ldc0, int ldc1)
{
    __shared__ ushort lA[2][128][64];   // 32 KB
    __shared__ ushort lB[128][64];      // 16 KB

    const int t    = threadIdx.x;
    const int m0   = blockIdx.y * 128;
    const int n0   = blockIdx.x * 128;
    const int wave = t >> 6;
    const int lane = t & 63;
    const int mw   = (wave & 1) * 64;
    const int nw   = (wave >> 1) * 64;
    const int l15  = lane & 15;
    const int l4   = lane >> 4;
    const int sw   = l15 & 7;
    GL_DEFS

    f32x4 acc[4][4];
#pragma unroll
    for (int i = 0; i < 4; ++i)
#pragma unroll
        for (int j = 0; j < 4; ++j)
            acc[i][j] = (f32x4){0.f, 0.f, 0.f, 0.f};

    for (int k0 = 0; k0 < K; k0 += 64) {
        __syncthreads();
        STAGE_GL(Ahi, lA[0], m0, K, k0)
        STAGE_GL(Alo, lA[1], m0, K, k0)
        STAGE_GL(Bf,  lB,    n0, K, k0)
        __syncthreads();
        COMPUTE_KS(0)
        COMPUTE_KS(1)
    }

#pragma unroll
    for (int i = 0; i < 4; ++i) {
        const int rowg = m0 + mw + i * 16 + l4 * 4;
#pragma unroll
        for (int j = 0; j < 4; ++j) {
            const int colg = n0 + nw + j * 16 + l15;
            if (colg < nsplit) {
#pragma unroll
                for (int v = 0; v < 4; ++v)
                    C0[(size_t)(rowg + v) * ldc0 + colg] = acc[i][j][v];
            } else {
                const int cc = colg - nsplit;
#pragma unroll
                for (int v = 0; v < 4; ++v) {
                    const float r = acc[i][j][v];
                    C1[(size_t)(rowg + v) * ldc1 + cc] =
                        r * fast_rcp(1.f + fast_exp2(-LOG2E * r));
                }
            }
        }
    }
}

// ---------------------------------------------------------------------------
// split-K MFMA GEMM for x_dbl = u @ W_x (N padded 96->128), fp16 2-pass.
// ---------------------------------------------------------------------------
__global__ __launch_bounds__(256) void gemm_wx_mfma(
    const ushort* __restrict__ Ahi, const ushort* __restrict__ Alo,
    const ushort* __restrict__ Bf, float* __restrict__ part)
{
    __shared__ ushort lA[2][128][64];
    __shared__ ushort lB[128][64];

    const int t    = threadIdx.x;
    const int kb   = blockIdx.x;
    const int m0   = blockIdx.y * 128;
    const int wave = t >> 6;
    const int lane = t & 63;
    const int mw   = (wave & 1) * 64;
    const int nw   = (wave >> 1) * 64;
    const int l15  = lane & 15;
    const int l4   = lane >> 4;
    const int sw   = l15 & 7;
    const int kbase = kb * WX_KSEG;
    GL_DEFS

    f32x4 acc[4][4];
#pragma unroll
    for (int i = 0; i < 4; ++i)
#pragma unroll
        for (int j = 0; j < 4; ++j)
            acc[i][j] = (f32x4){0.f, 0.f, 0.f, 0.f};

    for (int k0 = 0; k0 < WX_KSEG; k0 += 64) {
        __syncthreads();
        STAGE_GL(Ahi, lA[0], m0, D_IN, kbase + k0)
        STAGE_GL(Alo, lA[1], m0, D_IN, kbase + k0)
        STAGE_GL(Bf,  lB,    0,  D_IN, kbase + k0)
        __syncthreads();
        COMPUTE_KS(0)
        COMPUTE_KS(1)
    }

#pragma unroll
    for (int i = 0; i < 4; ++i) {
        const int rowg = m0 + mw + i * 16 + l4 * 4;
#pragma unroll
        for (int j = 0; j < 4; ++j) {
            const int colg = nw + j * 16 + l15;
#pragma unroll
            for (int v = 0; v < 4; ++v)
                part[((size_t)kb * SEQ + rowg + v) * XDBL_LD + colg] =
                    acc[i][j][v];
        }
    }
}

// Fixed-order reduction of the WX_KSPLIT partials -> xdbl [SEQ][XDBL_LD].
__global__ __launch_bounds__(256) void wx_reduce(
    const float* __restrict__ part, float* __restrict__ xdbl)
{
    const size_t i = (size_t)(blockIdx.x * 256 + threadIdx.x) * 4;
    float4 s = *(const float4*)&part[i];
#pragma unroll
    for (int kb = 1; kb < WX_KSPLIT; ++kb) {
        const float4 v = *(const float4*)&part[(size_t)kb * SEQ * XDBL_LD + i];
        s.x += v.x; s.y += v.y; s.z += v.z; s.w += v.w;
    }
    *(float4*)&xdbl[i] = s;
}

// ---------------------------------------------------------------------------
// split-K=4 MFMA GEMM for out = yg @ W_out, fp16 2-pass.
// ---------------------------------------------------------------------------
__global__ __launch_bounds__(256) void gemm_out_mfma(
    const ushort* __restrict__ Ahi, const ushort* __restrict__ Alo,
    const ushort* __restrict__ Bf,
    float* __restrict__ p01, float* __restrict__ p23)
{
    __shared__ ushort lA[2][128][64];
    __shared__ ushort lB[128][64];

    const int t    = threadIdx.x;
    const int n0   = blockIdx.x * 128;
    const int m0   = blockIdx.y * 128;
    const int kb   = blockIdx.z;
    const int wave = t >> 6;
    const int lane = t & 63;
    const int mw   = (wave & 1) * 64;
    const int nw   = (wave >> 1) * 64;
    const int l15  = lane & 15;
    const int l4   = lane >> 4;
    const int sw   = l15 & 7;
    const int kbase = kb * OUT_KSEG;
    GL_DEFS

    f32x4 acc[4][4];
#pragma unroll
    for (int i = 0; i < 4; ++i)
#pragma unroll
        for (int j = 0; j < 4; ++j)
            acc[i][j] = (f32x4){0.f, 0.f, 0.f, 0.f};

    for (int k0 = 0; k0 < OUT_KSEG; k0 += 64) {
        __syncthreads();
        STAGE_GL(Ahi, lA[0], m0, D_IN, kbase + k0)
        STAGE_GL(Alo, lA[1], m0, D_IN, kbase + k0)
        STAGE_GL(Bf,  lB,    n0, D_IN, kbase + k0)
        __syncthreads();
        COMPUTE_KS(0)
        COMPUTE_KS(1)
    }

    float* base = (kb & 2) ? p23 : p01;
    base += (size_t)(kb & 1) * SEQ * D_MODEL;
#pragma unroll
    for (int i = 0; i < 4; ++i) {
        const int rowg = m0 + mw + i * 16 + l4 * 4;
#pragma unroll
        for (int j = 0; j < 4; ++j) {
            const int colg = n0 + nw + j * 16 + l15;
#pragma unroll
            for (int v = 0; v < 4; ++v)
                base[(size_t)(rowg + v) * D_MODEL + colg] = acc[i][j][v];
        }
    }
}

// Fixed-order reduce of the 4 output partials -> out [SEQ][D_MODEL].
__global__ __launch_bounds__(256) void out_reduce(
    const float* __restrict__ p01, const float* __restrict__ p23,
    float* __restrict__ out)
{
    const size_t i = (size_t)(blockIdx.x * 256 + threadIdx.x) * 4;
    const size_t MN = (size_t)SEQ * D_MODEL;
    const float4 a = *(const float4*)&p01[i];
    const float4 b = *(const float4*)&p01[i + MN];
    const float4 c = *(const float4*)&p23[i];
    const float4 d = *(const float4*)&p23[i + MN];
    float4 s;
    s.x = ((a.x + b.x) + c.x) + d.x;
    s.y = ((a.y + b.y) + c.y) + d.y;
    s.z = ((a.z + b.z) + c.z) + d.z;
    s.w = ((a.w + b.w) + c.w) + d.w;
    *(float4*)&out[i] = s;
}

// ---------------------------------------------------------------------------
// delta GEMM, 64x64 tiles (K=64): 1024 blocks, ONE barrier, bounded unroll.
// Fused per-chunk double column sums (64-row tile == one chunk).
// ---------------------------------------------------------------------------
__global__ __launch_bounds__(256) void gemm_delta64(
    const float* __restrict__ A, const float* __restrict__ B,
    const float* __restrict__ bias, float* __restrict__ C,
    double* __restrict__ csumOut)
{
    __shared__ float At[64][68];
    __shared__ float Bs[64][68];
    __shared__ double dpart[16][64];

    const int t  = threadIdx.x;
    const int n0 = blockIdx.x * 64;
    const int m0 = blockIdx.y * 64;

    {
        const int r   = t >> 2;
        const int c16 = (t & 3) * 16;
#pragma unroll
        for (int q = 0; q < 4; ++q) {
            const float4 v =
                *(const float4*)&A[(size_t)(m0 + r) * XDBL_LD + c16 + q * 4];
            At[c16 + q * 4 + 0][r] = v.x;
            At[c16 + q * 4 + 1][r] = v.y;
            At[c16 + q * 4 + 2][r] = v.z;
            At[c16 + q * 4 + 3][r] = v.w;
        }
#pragma unroll
        for (int q = 0; q < 4; ++q)
            *(float4*)&Bs[r][c16 + q * 4] =
                *(const float4*)&B[(size_t)r * D_IN + n0 + c16 + q * 4];
    }
    __syncthreads();

    const int tx = t & 15;
    const int ty = t >> 4;
    float acc[4][4];
#pragma unroll
    for (int i = 0; i < 4; ++i)
#pragma unroll
        for (int j = 0; j < 4; ++j) acc[i][j] = 0.f;

#pragma unroll 1
    for (int k0 = 0; k0 < 64; k0 += 8) {
#pragma unroll
        for (int kk = 0; kk < 8; ++kk) {
            const int k = k0 + kk;
            const float4 a = *(const float4*)&At[k][ty * 4];
            const float4 b = *(const float4*)&Bs[k][tx * 4];
            const float av[4] = {a.x, a.y, a.z, a.w};
            const float bv[4] = {b.x, b.y, b.z, b.w};
#pragma unroll
            for (int i = 0; i < 4; ++i)
#pragma unroll
                for (int j = 0; j < 4; ++j)
                    acc[i][j] = fmaf(av[i], bv[j], acc[i][j]);
        }
    }

    double dsum[4];
#pragma unroll
    for (int j = 0; j < 4; ++j) dsum[j] = 0.0;
#pragma unroll
    for (int i = 0; i < 4; ++i) {
        float vals[4];
#pragma unroll
        for (int j = 0; j < 4; ++j) {
            float v = acc[i][j] + bias[n0 + tx * 4 + j];
            v = (v > 20.f) ? v : log1pf(__expf(v));   // softplus
            vals[j] = v;
            dsum[j] += (double)v;
        }
        *(float4*)&C[(size_t)(m0 + ty * 4 + i) * D_IN + n0 + tx * 4] =
            *(float4*)vals;
    }
#pragma unroll
    for (int j = 0; j < 4; ++j) dpart[ty][tx * 4 + j] = dsum[j];
    __syncthreads();
    if (t < 64) {
        double s = 0.0;
#pragma unroll
        for (int q = 0; q < 16; ++q) s += dpart[q][t];
        csumOut[(size_t)(m0 >> 6) * D_IN + n0 + t] = s;
    }
}

// ---------------------------------------------------------------------------
// Depthwise causal conv (K=3) + SiLU, fused with fp16 hi/lo split of u.
// ---------------------------------------------------------------------------
__global__ __launch_bounds__(256) void conv_silu_split(
    const float* __restrict__ xi, const float* __restrict__ cw,
    float* __restrict__ u, ushort* __restrict__ uhi, ushort* __restrict__ ulo)
{
    const int id = blockIdx.x * 256 + threadIdx.x;
    const int l = id >> 11;
    const int d = id & (D_IN - 1);
    const float w0 = cw[d * 3 + 0];
    const float w1 = cw[d * 3 + 1];
    const float w2 = cw[d * 3 + 2];
    const float x0  = xi[(size_t)l * D_IN + d];
    const float xm1 = (l >= 1) ? xi[(size_t)(l - 1) * D_IN + d] : 0.f;
    const float xm2 = (l >= 2) ? xi[(size_t)(l - 2) * D_IN + d] : 0.f;
    const float v = w0 * xm2 + w1 * xm1 + w2 * x0;
    const float s = fast_rcp(1.f + fast_exp2(-LOG2E * v));
    const float uu = v * s;
    u[id] = uu;
    const ushort h = f2h(uu);
    uhi[id] = h;
    ulo[id] = f2h(uu - h2f(h));
}

// ---------------------------------------------------------------------------
// Pass A (cumsum form), 2 states/lane, in-kernel sfx, HALF-CHUNK tiles:
// LDS = spA[32][32] float2 (8 KB) + sbA[32][8] float2 (0.5 KB) -> high
// occupancy. W0/W1 and the phase-2 double prefix P carry across halves in
// registers (same serial order as round 17 => bit-identical sfx).
// ---------------------------------------------------------------------------
__global__ __launch_bounds__(256) void scan_partA(
    const float* __restrict__ delta, const float* __restrict__ u,
    const double* __restrict__ csum, const float* __restrict__ xdbl,
    const float* __restrict__ Alog, float* __restrict__ Wc)
{
    __shared__ float2 spA[LH][DT];     // (du, delta->sfx)  8 KB
    __shared__ float2 sbA[LH][8];      //                   0.5 KB

    const int t  = threadIdx.x;
    const int c  = blockIdx.x;
    const int d0 = blockIdx.y * DT;

    // phase-2 state (threads 0..31, one per d): total S and running P
    double S = 0.0, P = 0.0;
    if (t < DT) {
        const int d = d0 + t;
        for (int c2 = 0; c2 < NCH; ++c2) {
            if (c2 == c) P = S;
            S += csum[(size_t)c2 * D_IN + d];
        }
    }

    const int dq = t >> 3;
    const int n8 = t & 7;
    const int d  = d0 + dq;
    const float An2a = -expf(Alog[d * N_STATE + n8]) * LOG2E;
    const float An2b = -expf(Alog[d * N_STATE + n8 + 8]) * LOG2E;

    float W0 = 0.f, W1 = 0.f;

    for (int hh = 0; hh < 2; ++hh) {
        const int rb = hh * LH;
#pragma unroll
        for (int q = 0; q < 4; ++q) {
            const int e = q * 256 + t;
            const int r = e >> 5, col = e & 31;
            const size_t row = (size_t)(c * LC + rb + r) * D_IN + d0 + col;
            const float dv = delta[row];
            spA[r][col] = make_float2(dv * u[row], dv);
        }
        {
            const int r = t >> 3, n8e = t & 7;
            const size_t base = (size_t)(c * LC + rb + r) * XDBL_LD + DT_RANK;
            sbA[r][n8e] = make_float2(xdbl[base + n8e], xdbl[base + 8 + n8e]);
        }
        __syncthreads();

        if (t < DT) {   // per-d double prefix -> sfx in LDS (order-identical)
            for (int i = 0; i < LH; ++i) {
                P += (double)spA[i][t].y;
                spA[i][t].y = (float)fmax(S - P, 0.0);
            }
        }
        __syncthreads();

#pragma unroll
        for (int i = 0; i < LH; ++i) {
            const float2 p = spA[i][dq];
            const float2 b = sbA[i][n8];
            W0 = fmaf(p.x * b.x, fast_exp2(An2a * p.y), W0);
            W1 = fmaf(p.x * b.y, fast_exp2(An2b * p.y), W1);
        }
        __syncthreads();   // before next half overwrites LDS
    }

    const size_t o = ((size_t)c * D_IN + d) * N_STATE + n8;
    Wc[o]     = W0;
    Wc[o + 8] = W1;
}

// ---------------------------------------------------------------------------
// Pass B: exclusive prefix over chunks (plain adds; cumsum form).
// ---------------------------------------------------------------------------
__global__ __launch_bounds__(256) void scan_combine(float* __restrict__ Wc)
{
    const int id = blockIdx.x * 256 + threadIdx.x;   // (d,n)
    float W = 0.f;
    for (int c = 0; c < NCH; ++c) {
        const size_t idx = (size_t)c * (D_IN * N_STATE) + id;
        const float w = Wc[idx];
        Wc[idx] = W;
        W += w;
    }
}

// ---------------------------------------------------------------------------
// Pass C (cumsum form), 2 states/lane, in-kernel sfx, HALF-CHUNK tiles,
// direct fp16 hi/lo yg output.  LDS = spack[32][32] float4 (16 KB) +
// sbc[32][8] float4 (2 KB) -> ~8 blocks/CU.
// ---------------------------------------------------------------------------
__global__ __launch_bounds__(256) void scan_partC(
    const float* __restrict__ delta, const float* __restrict__ u,
    const float* __restrict__ xdbl, const float* __restrict__ W0buf,
    const double* __restrict__ csum, const float* __restrict__ Alog,
    const float* __restrict__ Dvec, const float* __restrict__ rgbuf,
    ushort* __restrict__ ygh, ushort* __restrict__ ygl)
{
    __shared__ float4 spack[LH][DT];   // (du, delta->sfx, u, rg) 16 KB
    __shared__ float4 sbc[LH][8];      //  2 KB

    const int t  = threadIdx.x;
    const int c  = blockIdx.x;
    const int d0 = blockIdx.y * DT;

    double S = 0.0, P = 0.0;
    if (t < DT) {
        const int d = d0 + t;
        for (int c2 = 0; c2 < NCH; ++c2) {
            if (c2 == c) P = S;
            S += csum[(size_t)c2 * D_IN + d];
        }
    }

    const int dq = t >> 3;
    const int n8 = t & 7;
    const int d  = d0 + dq;
    const float An2a = -expf(Alog[d * N_STATE + n8]) * LOG2E;
    const float An2b = -expf(Alog[d * N_STATE + n8 + 8]) * LOG2E;
    const float Dd = Dvec[d];

    const size_t wo = ((size_t)c * D_IN + d) * N_STATE + n8;
    float W0 = W0buf[wo];
    float W1 = W0buf[wo + 8];

    for (int hh = 0; hh < 2; ++hh) {
        const int rb = hh * LH;
#pragma unroll
        for (int q = 0; q < 4; ++q) {
            const int e = q * 256 + t;
            const int r = e >> 5, col = e & 31;
            const size_t row = (size_t)(c * LC + rb + r) * D_IN + d0 + col;
            const float dv = delta[row];
            const float uv = u[row];
            spack[r][col] = make_float4(dv * uv, dv, uv, rgbuf[row]);
        }
        {
            const int r = t >> 3, n8e = t & 7;
            const size_t base = (size_t)(c * LC + rb + r) * XDBL_LD + DT_RANK;
            sbc[r][n8e] = make_float4(
                xdbl[base + n8e],     xdbl[base + 16 + n8e],
                xdbl[base + 8 + n8e], xdbl[base + 24 + n8e]);
        }
        __syncthreads();

        if (t < DT) {   // per-d double prefix -> sfx in LDS (order-identical)
            for (int i = 0; i < LH; ++i) {
                P += (double)spack[i][t].y;
                spack[i][t].y = (float)fmax(S - P, 0.0);
            }
        }
        __syncthreads();

#pragma unroll
        for (int i = 0; i < LH; ++i) {
            const float4 p  = spack[i][dq];
            const float4 bc = sbc[i][n8];
            const float E0 = fast_exp2(An2a * p.y);
            const float E1 = fast_exp2(An2b * p.y);
            W0 = fmaf(p.x * bc.x, E0, W0);
            W1 = fmaf(p.x * bc.z, E1, W1);
            const float xs0 = W0 * fast_rcp(E0 + 1e-12f);
            const float xs1 = W1 * fast_rcp(E1 + 1e-12f);
            float contrib = fmaf(xs0, bc.y, xs1 * bc.w);
            contrib = dpp_add<0xB1>(contrib);    // xor 1
            contrib = dpp_add<0x4E>(contrib);    // xor 2
            contrib = dpp_add<0x124>(contrib);   // row_ror:4
            if (n8 == 0) {
                const float ygv = fmaf(p.z, Dd, contrib) * p.w;
                const size_t row = (size_t)(c * LC + rb + i) * D_IN + d;
                const ushort h = f2h(ygv);
                ygh[row] = h;
                ygl[row] = f2h(ygv - h2f(h));
            }
        }
        __syncthreads();   // before next half overwrites LDS
    }
}

// ---------------------------------------------------------------------------
// Launch.  Workspace (74.5 MB peak, time-multiplexed; ws proven >= 84.9 MB):
//   [ 0    ,16.78M): xi -> wxp -> yg_hi/yg_lo (written by partC)
//   [16.78 ,33.55 ): rg (gemm1 epilogue) -> out partials p01
//   [33.55 ,50.33 ): x_hi/x_lo -> u (f32) -> wo (fp16)
//   [50.33 ,51.38 ): xdbl [2048][128] f32
//   [51.38 ,68.16 ): wi (fp16) -> u_hi/u_lo -> delta -> p23
//   [68.16 ,73.42 ): Wc/W0, csum
//   [73.42 ,74.47 ): wx (fp16)
// ---------------------------------------------------------------------------
extern "C" void kernel_launch(void* const* d_in, const int* in_sizes, int n_in,
                              void* d_out, int out_size, void* d_ws, size_t ws_size,
                              hipStream_t stream)
{
    const float* x      = (const float*)d_in[0];
    const float* W_in   = (const float*)d_in[1];
    const float* conv_w = (const float*)d_in[2];
    const float* W_x    = (const float*)d_in[3];
    const float* W_del  = (const float*)d_in[4];
    const float* b_del  = (const float*)d_in[5];
    const float* A_log  = (const float*)d_in[6];
    const float* Dv     = (const float*)d_in[7];
    const float* W_out  = (const float*)d_in[8];
    float* out = (float*)d_out;

    char* ws = (char*)d_ws;
    float*  xi    = (float*)(ws + 0);
    float*  wxp   = (float*)(ws + 0);
    ushort* yg_hi = (ushort*)(ws + 0);
    ushort* yg_lo = (ushort*)(ws + 8388608);
    float*  rg    = (float*)(ws + 16777216);   // gemm1 epilogue: res*sigmoid(res)
    float*  p01   = (float*)(ws + 16777216);
    ushort* x_hi  = (ushort*)(ws + 33554432);
    ushort* x_lo  = (ushort*)(ws + 37748736);
    float*  u     = (float*)(ws + 33554432);
    ushort* wo    = (ushort*)(ws + 33554432);  // [1024][2048] fp16
    float*  xdbl  = (float*)(ws + 50331648);
    ushort* wi    = (ushort*)(ws + 51380224);  // [4096][1024] fp16
    ushort* u_hi  = (ushort*)(ws + 51380224);
    ushort* u_lo  = (ushort*)(ws + 59768832);
    float*  delta = (float*)(ws + 51380224);
    float*  p23   = (float*)(ws + 51380224);
    float*  Wc    = (float*)(ws + 68157440);   // 4.19 MB
    double* csum  = (double*)(ws + 72351744);  // 0.52 MB
    ushort* wx    = (ushort*)(ws + 73416704);  // [128][2048] fp16

    // 1) W_in^T -> fp16
    trans_f16<<<dim3(4096 / 32, 1024 / 32), 256, 0, stream>>>(
        W_in, wi, 1024, 4096);

    // 2) x -> fp16 hi/lo
    split_f16<<<(SEQ * D_MODEL / 4) / 256, 256, 0, stream>>>(x, x_hi, x_lo);

    // 3) [xi | rg] = x @ W_in   (fp16 2-pass; C1 applies SiLU gate)
    gemm_mfma3<<<dim3(4096 / 128, 2048 / 128), 256, 0, stream>>>(
        x_hi, x_lo, wi, xi, rg, D_IN,
        SEQ, 2 * D_IN, D_MODEL, D_IN, D_IN);

    // 4) u = silu(conv(xi)) + u fp16 hi/lo (fused)
    conv_silu_split<<<(SEQ * D_IN) / 256, 256, 0, stream>>>(
        xi, conv_w, u, u_hi, u_lo);

    // 5) W_x^T padded -> fp16
    trans_f16_pad<<<dim3(XDBL_LD / 32, D_IN / 32), 256, 0, stream>>>(
        W_x, wx, D_IN, XDBL_W);

    // 6) x_dbl = u @ W_x  (split-K fp16 2-pass, fixed-order reduce)
    gemm_wx_mfma<<<dim3(WX_KSPLIT, SEQ / 128), 256, 0, stream>>>(
        u_hi, u_lo, wx, wxp);
    wx_reduce<<<(SEQ * XDBL_LD / 4) / 256, 256, 0, stream>>>(wxp, xdbl);

    // 7) delta = softplus(...) + fused per-chunk double column sums
    gemm_delta64<<<dim3(2048 / 64, 2048 / 64), 256, 0, stream>>>(
        xdbl, W_del, b_del, delta, csum);

    // 8) chunk-parallel scan (cumsum form, 2 states/lane, half-chunk tiles)
    scan_partA<<<dim3(NCH, D_IN / DT), 256, 0, stream>>>(
        delta, u, csum, xdbl, A_log, Wc);
    scan_combine<<<(D_IN * N_STATE) / 256, 256, 0, stream>>>(Wc);
    scan_partC<<<dim3(NCH, D_IN / DT), 256, 0, stream>>>(
        delta, u, xdbl, Wc, csum, A_log, Dv, rg, yg_hi, yg_lo);

    // 9) W_out^T -> fp16 (u dead; region reused)
    trans_f16<<<dim3(1024 / 32, 2048 / 32), 256, 0, stream>>>(
        W_out, wo, 2048, 1024);

    // 10) out = yg @ W_out  (split-K=4 fp16 2-pass; partials in dead regions)
    gemm_out_mfma<<<dim3(D_MODEL / 128, SEQ / 128, OUT_KSPLIT), 256, 0, stream>>>(
        yg_hi, yg_lo, wo, p01, p23);
    out_reduce<<<(SEQ * D_MODEL / 4) / 256, 256, 0, stream>>>(p01, p23, out);
}